// Round 4
// baseline (442.439 us; speedup 1.0000x reference)
//
#include <hip/hip_runtime.h>
#include <stdint.h>

#define S_LEN 2048
#define DIM   1024
#define NH    16
#define HD    64
#define BATCH 4
#define M_ROWS (BATCH * S_LEN)  // 8192

typedef __attribute__((ext_vector_type(8))) __bf16 bf16x8;
typedef __attribute__((ext_vector_type(4))) float  f32x4;

union Frag { bf16x8 v; uint4 q; };

__device__ __forceinline__ ushort f2bf(float f) {
  union { float f; unsigned u; } x; x.f = f;
  unsigned r = x.u + 0x7fffu + ((x.u >> 16) & 1u);  // RNE
  return (ushort)(r >> 16);
}
__device__ __forceinline__ ushort f2bf_n(float f) {
  union { __bf16 b; ushort u; } x; x.b = (__bf16)f; return x.u;
}

__device__ __forceinline__ f32x4 mfma16(const Frag& a, const Frag& b, f32x4 c) {
  return __builtin_amdgcn_mfma_f32_16x16x32_bf16(a.v, b.v, c, 0, 0, 0);
}

// async global->LDS, 16B per lane; LDS dest = wave-uniform base + lane*16
__device__ __forceinline__ void gld_lds16(const ushort* g, ushort* l) {
  __builtin_amdgcn_global_load_lds(
      (__attribute__((address_space(1))) void*)g,
      (__attribute__((address_space(3))) void*)l, 16, 0, 0);
}

// ---------------- casts ----------------
__global__ void cast_x_kernel(const float* __restrict__ src, ushort* __restrict__ dst) {
  int i = blockIdx.x * 256 + threadIdx.x;
  float4 f = ((const float4*)src)[i];
  ushort4 u; u.x = f2bf(f.x); u.y = f2bf(f.y); u.z = f2bf(f.z); u.w = f2bf(f.w);
  ((ushort4*)dst)[i] = u;
}

__global__ void cast_w_kernel(const float* __restrict__ w0, const float* __restrict__ w1,
                              const float* __restrict__ w2, const float* __restrict__ w3,
                              ushort* __restrict__ d0, ushort* __restrict__ d1,
                              ushort* __restrict__ d2, ushort* __restrict__ d3) {
  const float* s; ushort* d;
  int z = blockIdx.y;
  if (z == 0) { s = w0; d = d0; } else if (z == 1) { s = w1; d = d1; }
  else if (z == 2) { s = w2; d = d2; } else { s = w3; d = d3; }
  int i = blockIdx.x * 256 + threadIdx.x;
  float4 f = ((const float4*)s)[i];
  ushort4 u; u.x = f2bf(f.x); u.y = f2bf(f.y); u.z = f2bf(f.z); u.w = f2bf(f.w);
  ((ushort4*)d)[i] = u;
}

// ---------------- 128x128 bt-GEMM, BK=64, XOR-swizzled LDS, XCD-aware swizzle ----------------
// MODE 0: fused QKV, grid(24,64) flat-swizzled: writes Q (scaled, [B,S,D]),
//         K ([B,S,D]), V^T ([B,H,HD,S]).
// MODE 1: out-proj, grid(8,64) flat-swizzled: f32 out[m*DIM+e] + bias[e].
template <int MODE>
__global__ __launch_bounds__(256)
void gemm_bk64(const ushort* __restrict__ A,
               const ushort* __restrict__ B0, const ushort* __restrict__ B1,
               const ushort* __restrict__ B2,
               ushort* __restrict__ Qb, ushort* __restrict__ Kb, ushort* __restrict__ Vtb,
               float* __restrict__ outf, const float* __restrict__ bias, float scaleq) {
  __shared__ __align__(16) ushort As[128 * 64];
  __shared__ __align__(16) ushort Bs[128 * 64];
  const int K = DIM;
  int lane = threadIdx.x & 63, wave = threadIdx.x >> 6;
  int quad = lane >> 4, l15 = lane & 15;

  // XCD-aware swizzle: each XCD (lin%8) owns 8 consecutive row-groups so the
  // A row-block is fetched into exactly one XCD's L2.
  const int GX = (MODE == 0) ? 24 : 8;
  int lin = blockIdx.x + GX * blockIdx.y;
  int xcd = lin & 7, idx = lin >> 3;
  int by = xcd * 8 + idx / GX;
  int bx = idx % GX;

  int rowBase = by * 128;
  int wsel, colBase;
  const ushort* Bt;
  if (MODE == 0) {
    wsel = bx >> 3;
    colBase = (bx & 7) * 128;
    Bt = (wsel == 0) ? B0 : (wsel == 1) ? B1 : B2;
  } else {
    wsel = 0;
    colBase = bx * 128;
    Bt = B0;
  }
  int wm = (wave >> 1) * 64, wn = (wave & 1) * 64;

  const ushort* Ag = A + (size_t)rowBase * K;
  const ushort* Bg = Bt + (size_t)colBase * K;

  f32x4 acc[4][4];
#pragma unroll
  for (int i = 0; i < 4; i++)
#pragma unroll
    for (int j = 0; j < 4; j++) acc[i][j] = (f32x4){0.f, 0.f, 0.f, 0.f};

  for (int k0 = 0; k0 < K; k0 += 64) {
#pragma unroll
    for (int cc = 0; cc < 4; ++cc) {
      int c = wave * 4 + cc;
      int s = c * 64 + lane;
      int row = s >> 3;
      int c8 = (s & 7) ^ (row & 7);
      gld_lds16(Ag + (size_t)row * K + k0 + c8 * 8, &As[c * 512]);
      gld_lds16(Bg + (size_t)row * K + k0 + c8 * 8, &Bs[c * 512]);
    }
    __syncthreads();
    Frag af[4][2], bf[4][2];
#pragma unroll
    for (int t = 0; t < 4; t++) {
      int ar = wm + t * 16 + l15;
      int br = wn + t * 16 + l15;
#pragma unroll
      for (int kk = 0; kk < 2; kk++) {
        af[t][kk].q = *(const uint4*)&As[ar * 64 + (((kk * 4 + quad) ^ (ar & 7))) * 8];
        bf[t][kk].q = *(const uint4*)&Bs[br * 64 + (((kk * 4 + quad) ^ (br & 7))) * 8];
      }
    }
#pragma unroll
    for (int kk = 0; kk < 2; kk++)
#pragma unroll
      for (int i = 0; i < 4; i++)
#pragma unroll
        for (int j = 0; j < 4; j++) acc[i][j] = mfma16(af[i][kk], bf[j][kk], acc[i][j]);
    __syncthreads();
  }

#pragma unroll
  for (int i = 0; i < 4; i++) {
    int rowt = wm + i * 16 + quad * 4;
#pragma unroll
    for (int j = 0; j < 4; j++) {
      int e = colBase + wn + j * 16 + l15;
      if (MODE == 0) {
        if (wsel < 2) {
          // plain [B,S,D] = [m][e]: trivial addressing
          ushort* dst = wsel ? Kb : Qb;
          float sc = wsel ? 1.f : scaleq;
#pragma unroll
          for (int r = 0; r < 4; r++) {
            size_t m = (size_t)(rowBase + rowt + r);
            dst[m * DIM + e] = f2bf(acc[i][j][r] * sc);
          }
        } else {
          int h = e >> 6, hd = e & 63;
          int m0 = rowBase + rowt;
          int b = m0 >> 11, s0 = m0 & (S_LEN - 1);
          ushort4 u;
          u.x = f2bf(acc[i][j][0]); u.y = f2bf(acc[i][j][1]);
          u.z = f2bf(acc[i][j][2]); u.w = f2bf(acc[i][j][3]);
          *(ushort4*)&Vtb[((size_t)((b * NH + h) * HD + hd) << 11) + s0] = u;
        }
      } else {
        float bv = bias[e];
#pragma unroll
        for (int r = 0; r < 4; r++) {
          int m = rowBase + rowt + r;
          outf[(size_t)m * DIM + e] = acc[i][j][r] + bv;
        }
      }
    }
  }
}

// ---------------- flash attention (causal; S^T orientation; no-max streaming softmax) ----------------
// LDS = 32 KB: P buffer aliased into Ks (one extra barrier) -> 4 blocks/CU.
// Q,K: [B,S,D] (Q pre-scaled by log2e/sqrt(HD)); Vt: [B,H,HD,S]; Ctx: [B,S,D] bf16.
// grid (B*H, S/128); qt = 15 - blockIdx.y (heavy tiles first).
__global__ __launch_bounds__(256, 4)
void flash_attn(const ushort* __restrict__ Qb, const ushort* __restrict__ Kb,
                const ushort* __restrict__ Vtb, ushort* __restrict__ Ctx) {
  __shared__ __align__(16) ushort Ks[128 * 64];  // K tile / Q staging / per-wave P (4KB each)
  __shared__ __align__(16) ushort Vs[64 * 128];  // V^T tile, swizzled

  int lane = threadIdx.x & 63, wave = threadIdx.x >> 6;
  int quad = lane >> 4, l15 = lane & 15;
  int bh = blockIdx.x;
  int qt = (gridDim.y - 1) - blockIdx.y;
  int q0 = qt * 128, wq0 = wave * 32;
  int b = bh >> 4, h = bh & 15;

  const ushort* Qg = Qb + (size_t)b * S_LEN * DIM + h * HD;  // row stride DIM
  const ushort* Kg = Kb + (size_t)b * S_LEN * DIM + h * HD;
  const ushort* Vh = Vtb + (size_t)bh * HD * S_LEN;

  // ---- stage Q tile (swizzled) into Ks, pull B-frags into registers
#pragma unroll
  for (int cc = 0; cc < 4; ++cc) {
    int c = wave * 4 + cc;
    int s = c * 64 + lane;
    int row = s >> 3;
    int c8 = (s & 7) ^ (row & 7);
    gld_lds16(Qg + (size_t)(q0 + row) * DIM + c8 * 8, &Ks[c * 512]);
  }
  __syncthreads();
  Frag qf[2][2];  // B-frag: B[d][qrow]
#pragma unroll
  for (int it = 0; it < 2; ++it)
#pragma unroll
    for (int ks = 0; ks < 2; ++ks) {
      int row = wq0 + it * 16 + l15;
      int c8 = (ks * 4 + quad) ^ (row & 7);
      qf[it][ks].q = *(const uint4*)&Ks[row * 64 + c8 * 8];
    }
  __syncthreads();

  float lst[2] = {0.f, 0.f};
  f32x4 oacc[2][4];
#pragma unroll
  for (int it = 0; it < 2; ++it)
#pragma unroll
    for (int dt = 0; dt < 4; ++dt) oacc[it][dt] = (f32x4){0.f, 0.f, 0.f, 0.f};

  ushort* Pw = &Ks[wave * 2048];  // per-wave 16x128 P slice, aliases Ks

  for (int kt = 0; kt <= qt; ++kt) {
    // ---- stage K (row stride DIM) and V^T, both XOR-swizzled
#pragma unroll
    for (int cc = 0; cc < 4; ++cc) {
      int c = wave * 4 + cc;
      int s = c * 64 + lane;
      int krow = s >> 3;
      int kc8 = (s & 7) ^ (krow & 7);
      gld_lds16(Kg + (size_t)(kt * 128 + krow) * DIM + kc8 * 8, &Ks[c * 512]);
      int vrow = s >> 4;
      int vc8 = (s & 15) ^ (vrow & 15);
      gld_lds16(Vh + (size_t)vrow * S_LEN + kt * 128 + vc8 * 8, &Vs[c * 512]);
    }
    __syncthreads();  // staging visible

    // ---- S^T = K · Q^T
    f32x4 sacc[2][8];
#pragma unroll
    for (int jt = 0; jt < 8; ++jt) {
      int row = jt * 16 + l15;
      Frag kf0, kf1;
      kf0.q = *(const uint4*)&Ks[row * 64 + ((quad) ^ (row & 7)) * 8];
      kf1.q = *(const uint4*)&Ks[row * 64 + ((4 + quad) ^ (row & 7)) * 8];
#pragma unroll
      for (int it = 0; it < 2; ++it) {
        f32x4 a = (f32x4){0.f, 0.f, 0.f, 0.f};
        a = mfma16(kf0, qf[it][0], a);
        a = mfma16(kf1, qf[it][1], a);
        sacc[it][jt] = a;
      }
    }
    __syncthreads();  // all waves done reading Ks -> Ks becomes P space

    // ---- causal mask on the diagonal tile only
    if (kt == qt) {
#pragma unroll
      for (int it = 0; it < 2; ++it)
#pragma unroll
        for (int jt = 0; jt < 8; ++jt)
#pragma unroll
          for (int r = 0; r < 4; ++r)
            if (jt * 16 + quad * 4 + r > wq0 + it * 16 + l15)
              sacc[it][jt][r] = -1e30f;
    }

    // ---- per-it: streaming softmax (no max), P write (swizzled 8B chunks), PV
#pragma unroll
    for (int it = 0; it < 2; ++it) {
      float ps = 0.f;
#pragma unroll
      for (int jt = 0; jt < 8; ++jt) {
        float p0 = exp2f(sacc[it][jt][0]);
        float p1 = exp2f(sacc[it][jt][1]);
        float p2 = exp2f(sacc[it][jt][2]);
        float p3 = exp2f(sacc[it][jt][3]);
        ps += (p0 + p1) + (p2 + p3);
        ushort4 u; u.x = f2bf_n(p0); u.y = f2bf_n(p1); u.z = f2bf_n(p2); u.w = f2bf_n(p3);
        int cw = (jt * 4 + quad) ^ (l15 << 1);
        *(ushort4*)&Pw[l15 * 128 + cw * 4] = u;  // P[m=l15][k chunk]
      }
      ps += __shfl_xor(ps, 16);
      ps += __shfl_xor(ps, 32);
      lst[it] += ps;

      // P A-frags (same-wave LDS RAW; in-order within wave)
      Frag pf[4];
#pragma unroll
      for (int ks = 0; ks < 4; ++ks) {
        int cr = (ks * 8 + quad * 2) ^ (l15 << 1);  // even -> 16B aligned pair
        pf[ks].q = *(const uint4*)&Pw[l15 * 128 + cr * 4];
      }

      // O += P V
#pragma unroll
      for (int dt = 0; dt < 4; ++dt) {
        f32x4 a = oacc[it][dt];
#pragma unroll
        for (int ks = 0; ks < 4; ++ks) {
          int row = dt * 16 + l15;
          Frag vf;
          vf.q = *(const uint4*)&Vs[row * 128 + (((ks * 4 + quad) ^ (row & 15))) * 8];
          a = mfma16(pf[ks], vf, a);
        }
        oacc[it][dt] = a;
      }
    }
    __syncthreads();  // P/V reads done before next restage
  }

  // ---- epilogue: normalize by l, store C-layout rows
#pragma unroll
  for (int it = 0; it < 2; ++it) {
    float linv = 1.f / lst[it];
    float lr[4];
#pragma unroll
    for (int r = 0; r < 4; ++r) lr[r] = __shfl(linv, quad * 4 + r);
#pragma unroll
    for (int r = 0; r < 4; ++r) {
      int qg = q0 + wq0 + it * 16 + quad * 4 + r;
      size_t base = ((size_t)(b * S_LEN + qg)) * DIM + h * HD;
#pragma unroll
      for (int dt = 0; dt < 4; ++dt)
        Ctx[base + dt * 16 + l15] = f2bf_n(oacc[it][dt][r] * lr[r]);
    }
  }
}

// ---------------- launch ----------------
extern "C" void kernel_launch(void* const* d_in, const int* in_sizes, int n_in,
                              void* d_out, int out_size, void* d_ws, size_t ws_size,
                              hipStream_t stream) {
  (void)in_sizes; (void)n_in; (void)out_size; (void)ws_size;
  const float* x  = (const float*)d_in[0];
  const float* Wq = (const float*)d_in[1];
  const float* Wk = (const float*)d_in[2];
  const float* Wv = (const float*)d_in[3];
  const float* Wo = (const float*)d_in[4];
  const float* bo = (const float*)d_in[5];
  float* out = (float*)d_out;

  ushort* Xb  = (ushort*)d_ws;                     // [8192][1024]
  ushort* Wqb = Xb  + (size_t)M_ROWS * DIM;
  ushort* Wkb = Wqb + (size_t)DIM * DIM;
  ushort* Wvb = Wkb + (size_t)DIM * DIM;
  ushort* Wob = Wvb + (size_t)DIM * DIM;
  ushort* Qb  = Wob + (size_t)DIM * DIM;           // [B,S,D] (pre-scaled)
  ushort* Kb  = Qb  + (size_t)M_ROWS * DIM;        // [B,S,D]
  ushort* Vtb = Kb  + (size_t)M_ROWS * DIM;        // [B,H,HD,S]
  ushort* Ctx = Vtb + (size_t)M_ROWS * DIM;        // [B,S,D]

  const float SCALE_Q = 0.18033688011112042f;  // log2(e) / sqrt(HD)

  cast_x_kernel<<<dim3(M_ROWS * DIM / 1024), 256, 0, stream>>>(x, Xb);
  cast_w_kernel<<<dim3(DIM * DIM / 1024, 4), 256, 0, stream>>>(Wq, Wk, Wv, Wo, Wqb, Wkb, Wvb, Wob);

  gemm_bk64<0><<<dim3(24, 64), 256, 0, stream>>>(Xb, Wqb, Wkb, Wvb, Qb, Kb, Vtb,
                                                 nullptr, nullptr, SCALE_Q);

  flash_attn<<<dim3(BATCH * NH, S_LEN / 128), 256, 0, stream>>>(Qb, Kb, Vtb, Ctx);

  gemm_bk64<1><<<dim3(8, 64), 256, 0, stream>>>(Ctx, Wob, nullptr, nullptr, nullptr, nullptr,
                                                nullptr, out, bo, 1.0f);
}

// Round 5
// 269.291 us; speedup vs baseline: 1.6430x; 1.6430x over previous
//
#include <hip/hip_runtime.h>
#include <stdint.h>

#define S_LEN 2048
#define DIM   1024
#define NH    16
#define HD    64
#define BATCH 4
#define M_ROWS (BATCH * S_LEN)  // 8192

typedef __attribute__((ext_vector_type(8))) __bf16 bf16x8;
typedef __attribute__((ext_vector_type(4))) float  f32x4;

union Frag { bf16x8 v; uint4 q; };

__device__ __forceinline__ ushort f2bf(float f) {
  union { float f; unsigned u; } x; x.f = f;
  unsigned r = x.u + 0x7fffu + ((x.u >> 16) & 1u);  // RNE
  return (ushort)(r >> 16);
}
__device__ __forceinline__ ushort f2bf_n(float f) {
  union { __bf16 b; ushort u; } x; x.b = (__bf16)f; return x.u;
}

__device__ __forceinline__ f32x4 mfma16(const Frag& a, const Frag& b, f32x4 c) {
  return __builtin_amdgcn_mfma_f32_16x16x32_bf16(a.v, b.v, c, 0, 0, 0);
}

// async global->LDS, 16B per lane; LDS dest = wave-uniform base + lane*16
__device__ __forceinline__ void gld_lds16(const ushort* g, ushort* l) {
  __builtin_amdgcn_global_load_lds(
      (__attribute__((address_space(1))) void*)g,
      (__attribute__((address_space(3))) void*)l, 16, 0, 0);
}

// ---------------- casts ----------------
__global__ void cast_x_kernel(const float* __restrict__ src, ushort* __restrict__ dst) {
  int i = blockIdx.x * 256 + threadIdx.x;
  float4 f = ((const float4*)src)[i];
  ushort4 u; u.x = f2bf(f.x); u.y = f2bf(f.y); u.z = f2bf(f.z); u.w = f2bf(f.w);
  ((ushort4*)dst)[i] = u;
}

__global__ void cast_w_kernel(const float* __restrict__ w0, const float* __restrict__ w1,
                              const float* __restrict__ w2, const float* __restrict__ w3,
                              ushort* __restrict__ d0, ushort* __restrict__ d1,
                              ushort* __restrict__ d2, ushort* __restrict__ d3) {
  const float* s; ushort* d;
  int z = blockIdx.y;
  if (z == 0) { s = w0; d = d0; } else if (z == 1) { s = w1; d = d1; }
  else if (z == 2) { s = w2; d = d2; } else { s = w3; d = d3; }
  int i = blockIdx.x * 256 + threadIdx.x;
  float4 f = ((const float4*)s)[i];
  ushort4 u; u.x = f2bf(f.x); u.y = f2bf(f.y); u.z = f2bf(f.z); u.w = f2bf(f.w);
  ((ushort4*)d)[i] = u;
}

// ---------------- 128x128 bt-GEMM, BK=64, XOR-swizzled LDS, XCD-aware swizzle ----------------
// MODE 0: fused QKV, grid(24,64): writes Q (scaled, [B,S,D]), K ([B,S,D]), V^T ([B,H,HD,S]).
// MODE 1: out-proj, grid(8,64): f32 out[m*DIM+e] + bias[e].
template <int MODE>
__global__ __launch_bounds__(256)
void gemm_bk64(const ushort* __restrict__ A,
               const ushort* __restrict__ B0, const ushort* __restrict__ B1,
               const ushort* __restrict__ B2,
               ushort* __restrict__ Qb, ushort* __restrict__ Kb, ushort* __restrict__ Vtb,
               float* __restrict__ outf, const float* __restrict__ bias, float scaleq) {
  __shared__ __align__(16) ushort As[128 * 64];
  __shared__ __align__(16) ushort Bs[128 * 64];
  const int K = DIM;
  int lane = threadIdx.x & 63, wave = threadIdx.x >> 6;
  int quad = lane >> 4, l15 = lane & 15;

  // XCD-aware swizzle: each XCD (lin%8) owns consecutive row-groups so the
  // A row-block is fetched into exactly one XCD's L2.
  const int GX = (MODE == 0) ? 24 : 8;
  int lin = blockIdx.x + GX * blockIdx.y;
  int xcd = lin & 7, idx = lin >> 3;
  int by = xcd * 8 + idx / GX;
  int bx = idx % GX;

  int rowBase = by * 128;
  int wsel, colBase;
  const ushort* Bt;
  if (MODE == 0) {
    wsel = bx >> 3;
    colBase = (bx & 7) * 128;
    Bt = (wsel == 0) ? B0 : (wsel == 1) ? B1 : B2;
  } else {
    wsel = 0;
    colBase = bx * 128;
    Bt = B0;
  }
  int wm = (wave >> 1) * 64, wn = (wave & 1) * 64;

  const ushort* Ag = A + (size_t)rowBase * K;
  const ushort* Bg = Bt + (size_t)colBase * K;

  f32x4 acc[4][4];
#pragma unroll
  for (int i = 0; i < 4; i++)
#pragma unroll
    for (int j = 0; j < 4; j++) acc[i][j] = (f32x4){0.f, 0.f, 0.f, 0.f};

  for (int k0 = 0; k0 < K; k0 += 64) {
#pragma unroll
    for (int cc = 0; cc < 4; ++cc) {
      int c = wave * 4 + cc;
      int s = c * 64 + lane;
      int row = s >> 3;
      int c8 = (s & 7) ^ (row & 7);
      gld_lds16(Ag + (size_t)row * K + k0 + c8 * 8, &As[c * 512]);
      gld_lds16(Bg + (size_t)row * K + k0 + c8 * 8, &Bs[c * 512]);
    }
    __syncthreads();
    Frag af[4][2], bf[4][2];
#pragma unroll
    for (int t = 0; t < 4; t++) {
      int ar = wm + t * 16 + l15;
      int br = wn + t * 16 + l15;
#pragma unroll
      for (int kk = 0; kk < 2; kk++) {
        af[t][kk].q = *(const uint4*)&As[ar * 64 + (((kk * 4 + quad) ^ (ar & 7))) * 8];
        bf[t][kk].q = *(const uint4*)&Bs[br * 64 + (((kk * 4 + quad) ^ (br & 7))) * 8];
      }
    }
#pragma unroll
    for (int kk = 0; kk < 2; kk++)
#pragma unroll
      for (int i = 0; i < 4; i++)
#pragma unroll
        for (int j = 0; j < 4; j++) acc[i][j] = mfma16(af[i][kk], bf[j][kk], acc[i][j]);
    __syncthreads();
  }

#pragma unroll
  for (int i = 0; i < 4; i++) {
    int rowt = wm + i * 16 + quad * 4;
#pragma unroll
    for (int j = 0; j < 4; j++) {
      int e = colBase + wn + j * 16 + l15;
      if (MODE == 0) {
        if (wsel < 2) {
          // plain [B,S,D] = [m][e]: trivial addressing
          ushort* dst = wsel ? Kb : Qb;
          float sc = wsel ? 1.f : scaleq;
#pragma unroll
          for (int r = 0; r < 4; r++) {
            size_t m = (size_t)(rowBase + rowt + r);
            dst[m * DIM + e] = f2bf(acc[i][j][r] * sc);
          }
        } else {
          int h = e >> 6, hd = e & 63;
          int m0 = rowBase + rowt;
          int b = m0 >> 11, s0 = m0 & (S_LEN - 1);
          ushort4 u;
          u.x = f2bf(acc[i][j][0]); u.y = f2bf(acc[i][j][1]);
          u.z = f2bf(acc[i][j][2]); u.w = f2bf(acc[i][j][3]);
          *(ushort4*)&Vtb[((size_t)((b * NH + h) * HD + hd) << 11) + s0] = u;
        }
      } else {
        float bv = bias[e];
#pragma unroll
        for (int r = 0; r < 4; r++) {
          int m = rowBase + rowt + r;
          outf[(size_t)m * DIM + e] = acc[i][j][r] + bv;
        }
      }
    }
  }
}

// ---------------- flash attention (causal; S^T orientation; no-max streaming softmax) ----------------
// LDS = 32 KB (P aliased into Ks). NO min-waves pin: with VGPR=128 the natural
// occupancy is 4 waves/EU = 4 blocks/CU; pinning it (R4) forced VGPR=64 + spills.
// Q,K: [B,S,D] (Q pre-scaled by log2e/sqrt(HD)); Vt: [B,H,HD,S]; Ctx: [B,S,D] bf16.
// grid (B*H, S/128); qt = 15 - blockIdx.y (heavy tiles first).
__global__ __launch_bounds__(256)
void flash_attn(const ushort* __restrict__ Qb, const ushort* __restrict__ Kb,
                const ushort* __restrict__ Vtb, ushort* __restrict__ Ctx) {
  __shared__ __align__(16) ushort Ks[128 * 64];  // K tile / Q staging / per-wave P (4KB each)
  __shared__ __align__(16) ushort Vs[64 * 128];  // V^T tile, swizzled

  int lane = threadIdx.x & 63, wave = threadIdx.x >> 6;
  int quad = lane >> 4, l15 = lane & 15;
  int bh = blockIdx.x;
  int qt = (gridDim.y - 1) - blockIdx.y;
  int q0 = qt * 128, wq0 = wave * 32;
  int b = bh >> 4, h = bh & 15;

  const ushort* Qg = Qb + (size_t)b * S_LEN * DIM + h * HD;  // row stride DIM
  const ushort* Kg = Kb + (size_t)b * S_LEN * DIM + h * HD;
  const ushort* Vh = Vtb + (size_t)bh * HD * S_LEN;

  // ---- stage Q tile (swizzled) into Ks, pull B-frags into registers
#pragma unroll
  for (int cc = 0; cc < 4; ++cc) {
    int c = wave * 4 + cc;
    int s = c * 64 + lane;
    int row = s >> 3;
    int c8 = (s & 7) ^ (row & 7);
    gld_lds16(Qg + (size_t)(q0 + row) * DIM + c8 * 8, &Ks[c * 512]);
  }
  __syncthreads();
  Frag qf[2][2];  // B-frag: B[d][qrow]
#pragma unroll
  for (int it = 0; it < 2; ++it)
#pragma unroll
    for (int ks = 0; ks < 2; ++ks) {
      int row = wq0 + it * 16 + l15;
      int c8 = (ks * 4 + quad) ^ (row & 7);
      qf[it][ks].q = *(const uint4*)&Ks[row * 64 + c8 * 8];
    }
  __syncthreads();

  float lst[2] = {0.f, 0.f};
  f32x4 oacc[2][4];
#pragma unroll
  for (int it = 0; it < 2; ++it)
#pragma unroll
    for (int dt = 0; dt < 4; ++dt) oacc[it][dt] = (f32x4){0.f, 0.f, 0.f, 0.f};

  ushort* Pw = &Ks[wave * 2048];  // per-wave 16x128 P slice, aliases Ks

  for (int kt = 0; kt <= qt; ++kt) {
    // ---- stage K (row stride DIM) and V^T, both XOR-swizzled
#pragma unroll
    for (int cc = 0; cc < 4; ++cc) {
      int c = wave * 4 + cc;
      int s = c * 64 + lane;
      int krow = s >> 3;
      int kc8 = (s & 7) ^ (krow & 7);
      gld_lds16(Kg + (size_t)(kt * 128 + krow) * DIM + kc8 * 8, &Ks[c * 512]);
      int vrow = s >> 4;
      int vc8 = (s & 15) ^ (vrow & 15);
      gld_lds16(Vh + (size_t)vrow * S_LEN + kt * 128 + vc8 * 8, &Vs[c * 512]);
    }
    __syncthreads();  // staging visible

    // ---- S^T = K · Q^T
    f32x4 sacc[2][8];
#pragma unroll
    for (int jt = 0; jt < 8; ++jt) {
      int row = jt * 16 + l15;
      Frag kf0, kf1;
      kf0.q = *(const uint4*)&Ks[row * 64 + ((quad) ^ (row & 7)) * 8];
      kf1.q = *(const uint4*)&Ks[row * 64 + ((4 + quad) ^ (row & 7)) * 8];
#pragma unroll
      for (int it = 0; it < 2; ++it) {
        f32x4 a = (f32x4){0.f, 0.f, 0.f, 0.f};
        a = mfma16(kf0, qf[it][0], a);
        a = mfma16(kf1, qf[it][1], a);
        sacc[it][jt] = a;
      }
    }
    __syncthreads();  // all waves done reading Ks -> Ks becomes P space

    // ---- causal mask on the diagonal tile only
    if (kt == qt) {
#pragma unroll
      for (int it = 0; it < 2; ++it)
#pragma unroll
        for (int jt = 0; jt < 8; ++jt)
#pragma unroll
          for (int r = 0; r < 4; ++r)
            if (jt * 16 + quad * 4 + r > wq0 + it * 16 + l15)
              sacc[it][jt][r] = -1e30f;
    }

    // ---- per-it: streaming softmax (no max), P write (swizzled 8B chunks), PV
#pragma unroll
    for (int it = 0; it < 2; ++it) {
      float ps = 0.f;
#pragma unroll
      for (int jt = 0; jt < 8; ++jt) {
        float p0 = exp2f(sacc[it][jt][0]);
        float p1 = exp2f(sacc[it][jt][1]);
        float p2 = exp2f(sacc[it][jt][2]);
        float p3 = exp2f(sacc[it][jt][3]);
        ps += (p0 + p1) + (p2 + p3);
        ushort4 u; u.x = f2bf_n(p0); u.y = f2bf_n(p1); u.z = f2bf_n(p2); u.w = f2bf_n(p3);
        int cw = (jt * 4 + quad) ^ (l15 << 1);
        *(ushort4*)&Pw[l15 * 128 + cw * 4] = u;  // P[m=l15][k chunk]
      }
      ps += __shfl_xor(ps, 16);
      ps += __shfl_xor(ps, 32);
      lst[it] += ps;

      // P A-frags (same-wave LDS RAW; in-order within wave)
      Frag pf[4];
#pragma unroll
      for (int ks = 0; ks < 4; ++ks) {
        int cr = (ks * 8 + quad * 2) ^ (l15 << 1);  // even -> 16B aligned pair
        pf[ks].q = *(const uint4*)&Pw[l15 * 128 + cr * 4];
      }

      // O += P V
#pragma unroll
      for (int dt = 0; dt < 4; ++dt) {
        f32x4 a = oacc[it][dt];
#pragma unroll
        for (int ks = 0; ks < 4; ++ks) {
          int row = dt * 16 + l15;
          Frag vf;
          vf.q = *(const uint4*)&Vs[row * 128 + (((ks * 4 + quad) ^ (row & 15))) * 8];
          a = mfma16(pf[ks], vf, a);
        }
        oacc[it][dt] = a;
      }
    }
    __syncthreads();  // P/V reads done before next restage
  }

  // ---- epilogue: normalize by l, store C-layout rows
#pragma unroll
  for (int it = 0; it < 2; ++it) {
    float linv = 1.f / lst[it];
    float lr[4];
#pragma unroll
    for (int r = 0; r < 4; ++r) lr[r] = __shfl(linv, quad * 4 + r);
#pragma unroll
    for (int r = 0; r < 4; ++r) {
      int qg = q0 + wq0 + it * 16 + quad * 4 + r;
      size_t base = ((size_t)(b * S_LEN + qg)) * DIM + h * HD;
#pragma unroll
      for (int dt = 0; dt < 4; ++dt)
        Ctx[base + dt * 16 + l15] = f2bf_n(oacc[it][dt][r] * lr[r]);
    }
  }
}

// ---------------- launch ----------------
extern "C" void kernel_launch(void* const* d_in, const int* in_sizes, int n_in,
                              void* d_out, int out_size, void* d_ws, size_t ws_size,
                              hipStream_t stream) {
  (void)in_sizes; (void)n_in; (void)out_size; (void)ws_size;
  const float* x  = (const float*)d_in[0];
  const float* Wq = (const float*)d_in[1];
  const float* Wk = (const float*)d_in[2];
  const float* Wv = (const float*)d_in[3];
  const float* Wo = (const float*)d_in[4];
  const float* bo = (const float*)d_in[5];
  float* out = (float*)d_out;

  ushort* Xb  = (ushort*)d_ws;                     // [8192][1024]
  ushort* Wqb = Xb  + (size_t)M_ROWS * DIM;
  ushort* Wkb = Wqb + (size_t)DIM * DIM;
  ushort* Wvb = Wkb + (size_t)DIM * DIM;
  ushort* Wob = Wvb + (size_t)DIM * DIM;
  ushort* Qb  = Wob + (size_t)DIM * DIM;           // [B,S,D] (pre-scaled)
  ushort* Kb  = Qb  + (size_t)M_ROWS * DIM;        // [B,S,D]
  ushort* Vtb = Kb  + (size_t)M_ROWS * DIM;        // [B,H,HD,S]
  ushort* Ctx = Vtb + (size_t)M_ROWS * DIM;        // [B,S,D]

  const float SCALE_Q = 0.18033688011112042f;  // log2(e) / sqrt(HD)

  cast_x_kernel<<<dim3(M_ROWS * DIM / 1024), 256, 0, stream>>>(x, Xb);
  cast_w_kernel<<<dim3(DIM * DIM / 1024, 4), 256, 0, stream>>>(Wq, Wk, Wv, Wo, Wqb, Wkb, Wvb, Wob);

  gemm_bk64<0><<<dim3(24, 64), 256, 0, stream>>>(Xb, Wqb, Wkb, Wvb, Qb, Kb, Vtb,
                                                 nullptr, nullptr, SCALE_Q);

  flash_attn<<<dim3(BATCH * NH, S_LEN / 128), 256, 0, stream>>>(Qb, Kb, Vtb, Ctx);

  gemm_bk64<1><<<dim3(8, 64), 256, 0, stream>>>(Ctx, Wob, nullptr, nullptr, nullptr, nullptr,
                                                nullptr, out, bo, 1.0f);
}